// Round 8
// baseline (580.245 us; speedup 1.0000x reference)
//
#include <hip/hip_runtime.h>

#define TOKENS 8192
#define INF 512
#define HIDDEN 1024
#define NEXP 16

typedef short bh4 __attribute__((ext_vector_type(4)));
typedef short bh8 __attribute__((ext_vector_type(8)));
typedef float f32x4 __attribute__((ext_vector_type(4)));

__device__ __forceinline__ short f2b(float f) {
  union { float f; unsigned u; } v; v.f = f;
  unsigned r = v.u + 0x7FFFu + ((v.u >> 16) & 1u);
  return (short)(r >> 16);
}
__device__ __forceinline__ float b2f(short h) {
  union { unsigned u; float f; } v; v.u = ((unsigned)(unsigned short)h) << 16;
  return v.f;
}
__device__ __forceinline__ float silu_f(float x) { return x / (1.f + __expf(-x)); }

// MFMA via inline asm; D tied to C with "+v".
__device__ __forceinline__ f32x4 mfma_16x16x32_bf16(bh8 a, bh8 b, f32x4 c) {
  asm("v_mfma_f32_16x16x32_bf16 %0, %1, %2, %0" : "+v"(c) : "v"(a), "v"(b));
  return c;
}

// ---------------- fp32 -> bf16 convert (vectorized) ----------------
__global__ __launch_bounds__(256) void convert_kernel(const float* __restrict__ in,
                                                      short* __restrict__ out, int n) {
  int nv = n >> 2;
  int stride = gridDim.x * blockDim.x;
  for (int i = blockIdx.x * blockDim.x + threadIdx.x; i < nv; i += stride) {
    float4 v = ((const float4*)in)[i];
    bh4 o;
    o[0] = f2b(v.x); o[1] = f2b(v.y); o[2] = f2b(v.z); o[3] = f2b(v.w);
    *(bh4*)(out + (size_t)i * 4) = o;
  }
}

// ---------------- batched transpose fp32 [R][C] -> bf16 [C][R] ----------------
__global__ __launch_bounds__(256) void transpose_kernel(const float* __restrict__ in,
                                                        short* __restrict__ out,
                                                        int R, int C) {
  __shared__ float tile[32][33];
  size_t base = (size_t)blockIdx.z * (size_t)R * (size_t)C;
  int c0 = blockIdx.x * 32, r0 = blockIdx.y * 32;
  int tx = threadIdx.x, ty = threadIdx.y;  // block (32,8)
  #pragma unroll
  for (int i = 0; i < 32; i += 8)
    tile[ty + i][tx] = in[base + (size_t)(r0 + ty + i) * C + (c0 + tx)];
  __syncthreads();
  #pragma unroll
  for (int i = 0; i < 32; i += 8)
    out[base + (size_t)(c0 + ty + i) * R + (r0 + tx)] = f2b(tile[tx][ty + i]);
}

// ---------------- 128x128-tile bf16 MFMA GEMM, z-batched over 17 jobs ----------------
// Round-6 verified kernel (swapped-operand MFMA: D m=l15, n=quad*4+r; XOR-swizzled
// LDS both-sides; M-strip XCD remap). Only change: __launch_bounds__(256,4).
// acc lives in 64 AGPRs (unified file); at 68 arch-VGPRs total was 132 > 128 ->
// 3 waves/SIMD. Forcing 4 waves/SIMD (total <=128) shaves ~4 arch regs ->
// occupancy 12 -> 16 waves/CU to better hide the vmcnt-drain barrier stall.
__global__ __launch_bounds__(256, 4) void gemm_moe(
    const short* __restrict__ Abase, size_t aStride,
    const short* __restrict__ BtE, const short* __restrict__ BtG, size_t bStride,
    const float* __restrict__ biasE, const float* __restrict__ biasG,
    short* __restrict__ Cbase, size_t cStride,
    const float* __restrict__ W3all, float* __restrict__ eout,
    int jobBase, int K, int phase) {
  __shared__ short As[128][64];
  __shared__ short Bs[128][64];
  const int z = blockIdx.z;
  const int job = jobBase + z;
  const short* A = Abase + (size_t)z * aStride;
  const short* Bt = (job < NEXP) ? BtE + (size_t)job * bStride : BtG;
  const float* bias = (job < NEXP) ? biasE + (size_t)job * HIDDEN : biasG;

  // XCD-aware remap (bijective; gx==8, gy==64): XCD bx owns M-tiles [8bx,8bx+8) x all N.
  const int bx = blockIdx.x, by = blockIdx.y;
  const int n0 = (by >> 3) * 128;
  const int m0 = (bx * 8 + (by & 7)) * 128;

  const int tid = threadIdx.x;
  const int lane = tid & 63;
  const int wid = tid >> 6;           // 0..3
  const int wm = (wid >> 1) * 64;
  const int wn = (wid & 1) * 64;
  const int quad = lane >> 4;
  const int l15 = lane & 15;

  f32x4 acc[4][4];
  #pragma unroll
  for (int i = 0; i < 4; ++i)
    #pragma unroll
    for (int j = 0; j < 4; ++j) {
      acc[i][j][0] = 0.f; acc[i][j][1] = 0.f; acc[i][j][2] = 0.f; acc[i][j][3] = 0.f;
    }

  const int srow = lane >> 3;                         // 0..7
  const int scol = ((lane & 7) << 3) ^ (srow << 3);   // pre-swizzled source col
  const short* aBase = A + (size_t)(m0 + wid * 32 + srow) * K + scol;
  const short* bBase = Bt + (size_t)(n0 + wid * 32 + srow) * K + scol;
  char* ldsA = (char*)&As[0][0];
  char* ldsB = (char*)&Bs[0][0];

  for (int kt = 0; kt < K; kt += 64) {
    __syncthreads();
    #pragma unroll
    for (int i = 0; i < 4; ++i) {
      __builtin_amdgcn_global_load_lds(
          (const __attribute__((address_space(1))) void*)(aBase + (size_t)(i * 8) * K + kt),
          (__attribute__((address_space(3))) void*)(ldsA + (wid * 4 + i) * 1024), 16, 0, 0);
      __builtin_amdgcn_global_load_lds(
          (const __attribute__((address_space(1))) void*)(bBase + (size_t)(i * 8) * K + kt),
          (__attribute__((address_space(3))) void*)(ldsB + (wid * 4 + i) * 1024), 16, 0, 0);
    }
    __syncthreads();

    #pragma unroll
    for (int ks = 0; ks < 2; ++ks) {
      bh8 af[4], bfr[4];
      #pragma unroll
      for (int mi = 0; mi < 4; ++mi) {
        int row = wm + mi * 16 + l15;
        int col = ((ks << 5) + (quad << 3)) ^ ((row & 7) << 3);
        af[mi] = *(const bh8*)&As[row][col];
      }
      #pragma unroll
      for (int ni = 0; ni < 4; ++ni) {
        int row = wn + ni * 16 + l15;
        int col = ((ks << 5) + (quad << 3)) ^ ((row & 7) << 3);
        bfr[ni] = *(const bh8*)&Bs[row][col];
      }
      // swapped operands: D layout m = l15, n = quad*4 + r
      #pragma unroll
      for (int mi = 0; mi < 4; ++mi)
        #pragma unroll
        for (int ni = 0; ni < 4; ++ni)
          acc[mi][ni] = mfma_16x16x32_bf16(bfr[ni], af[mi], acc[mi][ni]);
    }
  }

  // ---- Epilogue. Swapped D layout: m = l15, n = quad*4 + r ----
  if (phase == 1 || job == NEXP) {
    short* C = Cbase + (size_t)z * cStride;  // phase2 gating: cStride=0 -> g2b
    #pragma unroll
    for (int ni = 0; ni < 4; ++ni) {
      int nb = wn + ni * 16 + quad * 4;
      float4 bv4 = *(const float4*)&bias[n0 + nb];
      #pragma unroll
      for (int mi = 0; mi < 4; ++mi) {
        int mrow = m0 + wm + mi * 16 + l15;
        bh4 o;
        o[0] = f2b(silu_f(acc[mi][ni][0] + bv4.x));
        o[1] = f2b(silu_f(acc[mi][ni][1] + bv4.y));
        o[2] = f2b(silu_f(acc[mi][ni][2] + bv4.z));
        o[3] = f2b(silu_f(acc[mi][ni][3] + bv4.w));
        *(bh4*)&C[(size_t)mrow * HIDDEN + n0 + nb] = o;
      }
    }
  } else {
    const float* w3 = W3all + (size_t)job * HIDDEN;
    float4 bv4[4], wv4[4];
    #pragma unroll
    for (int ni = 0; ni < 4; ++ni) {
      int nb = n0 + wn + ni * 16 + quad * 4;
      bv4[ni] = *(const float4*)&bias[nb];
      wv4[ni] = *(const float4*)&w3[nb];
    }
    #pragma unroll
    for (int mi = 0; mi < 4; ++mi) {
      float s = 0.f;
      #pragma unroll
      for (int ni = 0; ni < 4; ++ni) {
        s += silu_f(acc[mi][ni][0] + bv4[ni].x) * wv4[ni].x;
        s += silu_f(acc[mi][ni][1] + bv4[ni].y) * wv4[ni].y;
        s += silu_f(acc[mi][ni][2] + bv4[ni].z) * wv4[ni].z;
        s += silu_f(acc[mi][ni][3] + bv4[ni].w) * wv4[ni].w;
      }
      // quads hold disjoint n-slices of the same row m = wm+mi*16+l15
      s += __shfl_xor(s, 16);
      s += __shfl_xor(s, 32);
      if (quad == 0) {
        int mrow = m0 + wm + mi * 16 + l15;
        atomicAdd(&eout[(size_t)mrow * NEXP + job], s);
      }
    }
  }
}

// ---------------- gating logits + softmax + final mix (verified) ----------------
__global__ __launch_bounds__(256) void final_kernel(
    const short* __restrict__ g2b, const float* __restrict__ Wg3,
    const float* __restrict__ bg3, const float* __restrict__ eout,
    const float* __restrict__ b3, float* __restrict__ out) {
  int row = blockIdx.x * 4 + (threadIdx.x >> 6);
  int lane = threadIdx.x & 63;
  float lp[16];
  #pragma unroll
  for (int j = 0; j < 16; ++j) lp[j] = 0.f;
  const short* grow = g2b + (size_t)row * HIDDEN;
  for (int t = 0; t < HIDDEN / 64; ++t) {
    int k = t * 64 + lane;
    float g = b2f(grow[k]);
    const float4* wr4 = (const float4*)(Wg3 + (size_t)k * NEXP);
    float4 wa = wr4[0], wb = wr4[1], wc = wr4[2], wd = wr4[3];
    lp[0]  = fmaf(g, wa.x, lp[0]);  lp[1]  = fmaf(g, wa.y, lp[1]);
    lp[2]  = fmaf(g, wa.z, lp[2]);  lp[3]  = fmaf(g, wa.w, lp[3]);
    lp[4]  = fmaf(g, wb.x, lp[4]);  lp[5]  = fmaf(g, wb.y, lp[5]);
    lp[6]  = fmaf(g, wb.z, lp[6]);  lp[7]  = fmaf(g, wb.w, lp[7]);
    lp[8]  = fmaf(g, wc.x, lp[8]);  lp[9]  = fmaf(g, wc.y, lp[9]);
    lp[10] = fmaf(g, wc.z, lp[10]); lp[11] = fmaf(g, wc.w, lp[11]);
    lp[12] = fmaf(g, wd.x, lp[12]); lp[13] = fmaf(g, wd.y, lp[13]);
    lp[14] = fmaf(g, wd.z, lp[14]); lp[15] = fmaf(g, wd.w, lp[15]);
  }
  #pragma unroll
  for (int j = 0; j < 16; ++j) {
    float v = lp[j];
    v += __shfl_xor(v, 1);  v += __shfl_xor(v, 2);  v += __shfl_xor(v, 4);
    v += __shfl_xor(v, 8);  v += __shfl_xor(v, 16); v += __shfl_xor(v, 32);
    lp[j] = v + bg3[j];
  }
  float mx = lp[0];
  #pragma unroll
  for (int j = 1; j < 16; ++j) mx = fmaxf(mx, lp[j]);
  float s = 0.f, accv = 0.f;
  #pragma unroll
  for (int j = 0; j < 16; ++j) {
    float p = __expf(lp[j] - mx);
    s += p;
    accv = fmaf(p, eout[(size_t)row * NEXP + j] + b3[j], accv);
  }
  if (lane == 0) out[row] = accv / s;
}

extern "C" void kernel_launch(void* const* d_in, const int* in_sizes, int n_in,
                              void* d_out, int out_size, void* d_ws, size_t ws_size,
                              hipStream_t stream) {
  const float* x   = (const float*)d_in[0];
  const float* W1  = (const float*)d_in[1];
  const float* b1  = (const float*)d_in[2];
  const float* W2  = (const float*)d_in[3];
  const float* b2  = (const float*)d_in[4];
  const float* W3  = (const float*)d_in[5];
  const float* b3  = (const float*)d_in[6];
  const float* Wg1 = (const float*)d_in[7];
  const float* bg1 = (const float*)d_in[8];
  const float* Wg2 = (const float*)d_in[9];
  const float* bg2 = (const float*)d_in[10];
  const float* Wg3 = (const float*)d_in[11];
  const float* bg3 = (const float*)d_in[12];
  float* out = (float*)d_out;

  // workspace: fixed region (~75.5 MB) + h1 slab capped at 8 slots (128 MB)
  // so slab + weights (~200 MB) stay L3-resident (256 MB Infinity Cache).
  char* p = (char*)d_ws;
  short* xb   = (short*)p; p += (size_t)TOKENS * INF * 2;
  short* W1t  = (short*)p; p += (size_t)NEXP * HIDDEN * INF * 2;
  short* W2t  = (short*)p; p += (size_t)NEXP * HIDDEN * HIDDEN * 2;
  short* Wg1t = (short*)p; p += (size_t)HIDDEN * INF * 2;
  short* Wg2t = (short*)p; p += (size_t)HIDDEN * HIDDEN * 2;
  short* g2b  = (short*)p; p += (size_t)TOKENS * HIDDEN * 2;
  float* eout = (float*)p; p += (size_t)TOKENS * NEXP * 4;
  size_t fixedBytes = (size_t)(p - (char*)d_ws);
  short* h1slab = (short*)p;
  const size_t SLOT_ELEMS = (size_t)TOKENS * HIDDEN;
  const size_t SLOT_BYTES = SLOT_ELEMS * 2;          // 16 MB
  size_t avail = ws_size > fixedBytes ? ws_size - fixedBytes : 0;
  int slots = (int)(avail / SLOT_BYTES);
  if (slots > 8) slots = 8;                          // L3-residency cap
  if (slots < 1) slots = 1;

  hipMemsetAsync(eout, 0, (size_t)TOKENS * NEXP * 4, stream);

  convert_kernel<<<1024, 256, 0, stream>>>(x, xb, TOKENS * INF);
  dim3 tb(32, 8);
  transpose_kernel<<<dim3(HIDDEN / 32, INF / 32, NEXP), tb, 0, stream>>>(W1, W1t, INF, HIDDEN);
  transpose_kernel<<<dim3(HIDDEN / 32, HIDDEN / 32, NEXP), tb, 0, stream>>>(W2, W2t, HIDDEN, HIDDEN);
  transpose_kernel<<<dim3(HIDDEN / 32, INF / 32, 1), tb, 0, stream>>>(Wg1, Wg1t, INF, HIDDEN);
  transpose_kernel<<<dim3(HIDDEN / 32, HIDDEN / 32, 1), tb, 0, stream>>>(Wg2, Wg2t, HIDDEN, HIDDEN);

  // 17 jobs: experts 0..15 + gating (job 16), processed in groups of `slots`
  for (int base = 0; base < NEXP + 1; base += slots) {
    int cnt = NEXP + 1 - base;
    if (cnt > slots) cnt = slots;
    dim3 gg(HIDDEN / 128, TOKENS / 128, cnt);  // (8, 64, cnt)
    // layer 1: A = xb (shared), C = h1 slab slot z
    gemm_moe<<<gg, 256, 0, stream>>>(xb, 0, W1t, Wg1t, (size_t)INF * HIDDEN,
                                     b1, bg1, h1slab, SLOT_ELEMS,
                                     nullptr, nullptr, base, INF, 1);
    // layer 2: A = h1 slot z; experts reduce into eout, gating writes g2b
    gemm_moe<<<gg, 256, 0, stream>>>(h1slab, SLOT_ELEMS, W2t, Wg2t, (size_t)HIDDEN * HIDDEN,
                                     b2, bg2, g2b, 0,
                                     W3, eout, base, HIDDEN, 2);
  }

  final_kernel<<<TOKENS / 4, 256, 0, stream>>>(g2b, Wg3, bg3, eout, b3, out);
}

// Round 9
// 569.129 us; speedup vs baseline: 1.0195x; 1.0195x over previous
//
#include <hip/hip_runtime.h>

#define TOKENS 8192
#define INF 512
#define HIDDEN 1024
#define NEXP 16

typedef short bh4 __attribute__((ext_vector_type(4)));
typedef short bh8 __attribute__((ext_vector_type(8)));
typedef float f32x4 __attribute__((ext_vector_type(4)));

__device__ __forceinline__ short f2b(float f) {
  union { float f; unsigned u; } v; v.f = f;
  unsigned r = v.u + 0x7FFFu + ((v.u >> 16) & 1u);
  return (short)(r >> 16);
}
__device__ __forceinline__ float b2f(short h) {
  union { unsigned u; float f; } v; v.u = ((unsigned)(unsigned short)h) << 16;
  return v.f;
}
__device__ __forceinline__ float silu_f(float x) { return x / (1.f + __expf(-x)); }

// MFMA via inline asm; D tied to C with "+v".
__device__ __forceinline__ f32x4 mfma_16x16x32_bf16(bh8 a, bh8 b, f32x4 c) {
  asm("v_mfma_f32_16x16x32_bf16 %0, %1, %2, %0" : "+v"(c) : "v"(a), "v"(b));
  return c;
}

// ---------------- fp32 -> bf16 convert (vectorized) ----------------
__global__ __launch_bounds__(256) void convert_kernel(const float* __restrict__ in,
                                                      short* __restrict__ out, int n) {
  int nv = n >> 2;
  int stride = gridDim.x * blockDim.x;
  for (int i = blockIdx.x * blockDim.x + threadIdx.x; i < nv; i += stride) {
    float4 v = ((const float4*)in)[i];
    bh4 o;
    o[0] = f2b(v.x); o[1] = f2b(v.y); o[2] = f2b(v.z); o[3] = f2b(v.w);
    *(bh4*)(out + (size_t)i * 4) = o;
  }
}

// ---------------- batched transpose fp32 [R][C] -> bf16 [C][R] ----------------
__global__ __launch_bounds__(256) void transpose_kernel(const float* __restrict__ in,
                                                        short* __restrict__ out,
                                                        int R, int C) {
  __shared__ float tile[32][33];
  size_t base = (size_t)blockIdx.z * (size_t)R * (size_t)C;
  int c0 = blockIdx.x * 32, r0 = blockIdx.y * 32;
  int tx = threadIdx.x, ty = threadIdx.y;  // block (32,8)
  #pragma unroll
  for (int i = 0; i < 32; i += 8)
    tile[ty + i][tx] = in[base + (size_t)(r0 + ty + i) * C + (c0 + tx)];
  __syncthreads();
  #pragma unroll
  for (int i = 0; i < 32; i += 8)
    out[base + (size_t)(c0 + ty + i) * R + (r0 + tx)] = f2b(tile[tx][ty + i]);
}

// ---------------- 128x128-tile bf16 MFMA GEMM, z-batched over 17 jobs ----------------
// Round-6 verified kernel + __launch_bounds__(256,4): acc lives in 64 AGPRs
// (unified file); forcing arch VGPRs <=64 gives total 128 -> 4 waves/SIMD.
__global__ __launch_bounds__(256, 4) void gemm_moe(
    const short* __restrict__ Abase, size_t aStride,
    const short* __restrict__ BtE, const short* __restrict__ BtG, size_t bStride,
    const float* __restrict__ biasE, const float* __restrict__ biasG,
    short* __restrict__ Cbase, size_t cStride,
    const float* __restrict__ W3all, float* __restrict__ eout,
    int jobBase, int K, int phase) {
  __shared__ short As[128][64];
  __shared__ short Bs[128][64];
  const int z = blockIdx.z;
  const int job = jobBase + z;
  const short* A = Abase + (size_t)z * aStride;
  const short* Bt = (job < NEXP) ? BtE + (size_t)job * bStride : BtG;
  const float* bias = (job < NEXP) ? biasE + (size_t)job * HIDDEN : biasG;

  // XCD-aware remap (bijective; gx==8, gy==64): XCD bx owns M-tiles [8bx,8bx+8) x all N.
  const int bx = blockIdx.x, by = blockIdx.y;
  const int n0 = (by >> 3) * 128;
  const int m0 = (bx * 8 + (by & 7)) * 128;

  const int tid = threadIdx.x;
  const int lane = tid & 63;
  const int wid = tid >> 6;           // 0..3
  const int wm = (wid >> 1) * 64;
  const int wn = (wid & 1) * 64;
  const int quad = lane >> 4;
  const int l15 = lane & 15;

  f32x4 acc[4][4];
  #pragma unroll
  for (int i = 0; i < 4; ++i)
    #pragma unroll
    for (int j = 0; j < 4; ++j) {
      acc[i][j][0] = 0.f; acc[i][j][1] = 0.f; acc[i][j][2] = 0.f; acc[i][j][3] = 0.f;
    }

  const int srow = lane >> 3;                         // 0..7
  const int scol = ((lane & 7) << 3) ^ (srow << 3);   // pre-swizzled source col
  const short* aBase = A + (size_t)(m0 + wid * 32 + srow) * K + scol;
  const short* bBase = Bt + (size_t)(n0 + wid * 32 + srow) * K + scol;
  char* ldsA = (char*)&As[0][0];
  char* ldsB = (char*)&Bs[0][0];

  for (int kt = 0; kt < K; kt += 64) {
    __syncthreads();
    #pragma unroll
    for (int i = 0; i < 4; ++i) {
      __builtin_amdgcn_global_load_lds(
          (const __attribute__((address_space(1))) void*)(aBase + (size_t)(i * 8) * K + kt),
          (__attribute__((address_space(3))) void*)(ldsA + (wid * 4 + i) * 1024), 16, 0, 0);
      __builtin_amdgcn_global_load_lds(
          (const __attribute__((address_space(1))) void*)(bBase + (size_t)(i * 8) * K + kt),
          (__attribute__((address_space(3))) void*)(ldsB + (wid * 4 + i) * 1024), 16, 0, 0);
    }
    __syncthreads();

    #pragma unroll
    for (int ks = 0; ks < 2; ++ks) {
      bh8 af[4], bfr[4];
      #pragma unroll
      for (int mi = 0; mi < 4; ++mi) {
        int row = wm + mi * 16 + l15;
        int col = ((ks << 5) + (quad << 3)) ^ ((row & 7) << 3);
        af[mi] = *(const bh8*)&As[row][col];
      }
      #pragma unroll
      for (int ni = 0; ni < 4; ++ni) {
        int row = wn + ni * 16 + l15;
        int col = ((ks << 5) + (quad << 3)) ^ ((row & 7) << 3);
        bfr[ni] = *(const bh8*)&Bs[row][col];
      }
      // swapped operands: D layout m = l15, n = quad*4 + r
      #pragma unroll
      for (int mi = 0; mi < 4; ++mi)
        #pragma unroll
        for (int ni = 0; ni < 4; ++ni)
          acc[mi][ni] = mfma_16x16x32_bf16(bfr[ni], af[mi], acc[mi][ni]);
    }
  }

  // ---- Epilogue. Swapped D layout: m = l15, n = quad*4 + r ----
  if (phase == 1 || job == NEXP) {
    short* C = Cbase + (size_t)z * cStride;  // phase2 gating: cStride=0 -> g2b
    #pragma unroll
    for (int ni = 0; ni < 4; ++ni) {
      int nb = wn + ni * 16 + quad * 4;
      float4 bv4 = *(const float4*)&bias[n0 + nb];
      #pragma unroll
      for (int mi = 0; mi < 4; ++mi) {
        int mrow = m0 + wm + mi * 16 + l15;
        bh4 o;
        o[0] = f2b(silu_f(acc[mi][ni][0] + bv4.x));
        o[1] = f2b(silu_f(acc[mi][ni][1] + bv4.y));
        o[2] = f2b(silu_f(acc[mi][ni][2] + bv4.z));
        o[3] = f2b(silu_f(acc[mi][ni][3] + bv4.w));
        *(bh4*)&C[(size_t)mrow * HIDDEN + n0 + nb] = o;
      }
    }
  } else {
    const float* w3 = W3all + (size_t)job * HIDDEN;
    float4 bv4[4], wv4[4];
    #pragma unroll
    for (int ni = 0; ni < 4; ++ni) {
      int nb = n0 + wn + ni * 16 + quad * 4;
      bv4[ni] = *(const float4*)&bias[nb];
      wv4[ni] = *(const float4*)&w3[nb];
    }
    #pragma unroll
    for (int mi = 0; mi < 4; ++mi) {
      float s = 0.f;
      #pragma unroll
      for (int ni = 0; ni < 4; ++ni) {
        s += silu_f(acc[mi][ni][0] + bv4[ni].x) * wv4[ni].x;
        s += silu_f(acc[mi][ni][1] + bv4[ni].y) * wv4[ni].y;
        s += silu_f(acc[mi][ni][2] + bv4[ni].z) * wv4[ni].z;
        s += silu_f(acc[mi][ni][3] + bv4[ni].w) * wv4[ni].w;
      }
      // quads hold disjoint n-slices of the same row m = wm+mi*16+l15
      s += __shfl_xor(s, 16);
      s += __shfl_xor(s, 32);
      if (quad == 0) {
        int mrow = m0 + wm + mi * 16 + l15;
        atomicAdd(&eout[(size_t)mrow * NEXP + job], s);
      }
    }
  }
}

// ---------------- gating logits + softmax + final mix (verified) ----------------
__global__ __launch_bounds__(256) void final_kernel(
    const short* __restrict__ g2b, const float* __restrict__ Wg3,
    const float* __restrict__ bg3, const float* __restrict__ eout,
    const float* __restrict__ b3, float* __restrict__ out) {
  int row = blockIdx.x * 4 + (threadIdx.x >> 6);
  int lane = threadIdx.x & 63;
  float lp[16];
  #pragma unroll
  for (int j = 0; j < 16; ++j) lp[j] = 0.f;
  const short* grow = g2b + (size_t)row * HIDDEN;
  for (int t = 0; t < HIDDEN / 64; ++t) {
    int k = t * 64 + lane;
    float g = b2f(grow[k]);
    const float4* wr4 = (const float4*)(Wg3 + (size_t)k * NEXP);
    float4 wa = wr4[0], wb = wr4[1], wc = wr4[2], wd = wr4[3];
    lp[0]  = fmaf(g, wa.x, lp[0]);  lp[1]  = fmaf(g, wa.y, lp[1]);
    lp[2]  = fmaf(g, wa.z, lp[2]);  lp[3]  = fmaf(g, wa.w, lp[3]);
    lp[4]  = fmaf(g, wb.x, lp[4]);  lp[5]  = fmaf(g, wb.y, lp[5]);
    lp[6]  = fmaf(g, wb.z, lp[6]);  lp[7]  = fmaf(g, wb.w, lp[7]);
    lp[8]  = fmaf(g, wc.x, lp[8]);  lp[9]  = fmaf(g, wc.y, lp[9]);
    lp[10] = fmaf(g, wc.z, lp[10]); lp[11] = fmaf(g, wc.w, lp[11]);
    lp[12] = fmaf(g, wd.x, lp[12]); lp[13] = fmaf(g, wd.y, lp[13]);
    lp[14] = fmaf(g, wd.z, lp[14]); lp[15] = fmaf(g, wd.w, lp[15]);
  }
  #pragma unroll
  for (int j = 0; j < 16; ++j) {
    float v = lp[j];
    v += __shfl_xor(v, 1);  v += __shfl_xor(v, 2);  v += __shfl_xor(v, 4);
    v += __shfl_xor(v, 8);  v += __shfl_xor(v, 16); v += __shfl_xor(v, 32);
    lp[j] = v + bg3[j];
  }
  float mx = lp[0];
  #pragma unroll
  for (int j = 1; j < 16; ++j) mx = fmaxf(mx, lp[j]);
  float s = 0.f, accv = 0.f;
  #pragma unroll
  for (int j = 0; j < 16; ++j) {
    float p = __expf(lp[j] - mx);
    s += p;
    accv = fmaf(p, eout[(size_t)row * NEXP + j] + b3[j], accv);
  }
  if (lane == 0) out[row] = accv / s;
}

extern "C" void kernel_launch(void* const* d_in, const int* in_sizes, int n_in,
                              void* d_out, int out_size, void* d_ws, size_t ws_size,
                              hipStream_t stream) {
  const float* x   = (const float*)d_in[0];
  const float* W1  = (const float*)d_in[1];
  const float* b1  = (const float*)d_in[2];
  const float* W2  = (const float*)d_in[3];
  const float* b2  = (const float*)d_in[4];
  const float* W3  = (const float*)d_in[5];
  const float* b3  = (const float*)d_in[6];
  const float* Wg1 = (const float*)d_in[7];
  const float* bg1 = (const float*)d_in[8];
  const float* Wg2 = (const float*)d_in[9];
  const float* bg2 = (const float*)d_in[10];
  const float* Wg3 = (const float*)d_in[11];
  const float* bg3 = (const float*)d_in[12];
  float* out = (float*)d_out;

  // workspace layout: fixed region (~75.5 MB) + h1 slab (17 x 16MB slots if ws allows)
  char* p = (char*)d_ws;
  short* xb   = (short*)p; p += (size_t)TOKENS * INF * 2;
  short* W1t  = (short*)p; p += (size_t)NEXP * HIDDEN * INF * 2;
  short* W2t  = (short*)p; p += (size_t)NEXP * HIDDEN * HIDDEN * 2;
  short* Wg1t = (short*)p; p += (size_t)HIDDEN * INF * 2;
  short* Wg2t = (short*)p; p += (size_t)HIDDEN * HIDDEN * 2;
  short* g2b  = (short*)p; p += (size_t)TOKENS * HIDDEN * 2;
  float* eout = (float*)p; p += (size_t)TOKENS * NEXP * 4;
  size_t fixedBytes = (size_t)(p - (char*)d_ws);
  short* h1slab = (short*)p;
  const size_t SLOT_ELEMS = (size_t)TOKENS * HIDDEN;
  const size_t SLOT_BYTES = SLOT_ELEMS * 2;          // 16 MB
  size_t avail = ws_size > fixedBytes ? ws_size - fixedBytes : 0;
  int slots = (int)(avail / SLOT_BYTES);
  if (slots > NEXP + 1) slots = NEXP + 1;
  if (slots < 1) slots = 1;

  hipMemsetAsync(eout, 0, (size_t)TOKENS * NEXP * 4, stream);

  convert_kernel<<<1024, 256, 0, stream>>>(x, xb, TOKENS * INF);
  dim3 tb(32, 8);
  transpose_kernel<<<dim3(HIDDEN / 32, INF / 32, NEXP), tb, 0, stream>>>(W1, W1t, INF, HIDDEN);
  transpose_kernel<<<dim3(HIDDEN / 32, HIDDEN / 32, NEXP), tb, 0, stream>>>(W2, W2t, HIDDEN, HIDDEN);
  transpose_kernel<<<dim3(HIDDEN / 32, INF / 32, 1), tb, 0, stream>>>(Wg1, Wg1t, INF, HIDDEN);
  transpose_kernel<<<dim3(HIDDEN / 32, HIDDEN / 32, 1), tb, 0, stream>>>(Wg2, Wg2t, HIDDEN, HIDDEN);

  // 17 jobs: experts 0..15 + gating (job 16), processed in groups of `slots`
  for (int base = 0; base < NEXP + 1; base += slots) {
    int cnt = NEXP + 1 - base;
    if (cnt > slots) cnt = slots;
    dim3 gg(HIDDEN / 128, TOKENS / 128, cnt);  // (8, 64, cnt)
    // layer 1: A = xb (shared), C = h1 slab slot z
    gemm_moe<<<gg, 256, 0, stream>>>(xb, 0, W1t, Wg1t, (size_t)INF * HIDDEN,
                                     b1, bg1, h1slab, SLOT_ELEMS,
                                     nullptr, nullptr, base, INF, 1);
    // layer 2: A = h1 slot z; experts reduce into eout, gating writes g2b
    gemm_moe<<<gg, 256, 0, stream>>>(h1slab, SLOT_ELEMS, W2t, Wg2t, (size_t)HIDDEN * HIDDEN,
                                     b2, bg2, g2b, 0,
                                     W3, eout, base, HIDDEN, 2);
  }

  final_kernel<<<TOKENS / 4, 256, 0, stream>>>(g2b, Wg3, bg3, eout, b3, out);
}